// Round 1
// 338.690 us; speedup vs baseline: 1.1719x; 1.1719x over previous
//
#include <hip/hip_runtime.h>
#include <stdint.h>

// Problem constants: B=8, S=4096, H=1024, E=8 -> N = 32768 tokens.
#define HDIM 1024
#define NEXP 8
#define NTOK 32768
#define BM 128
#define BN 128
#define BK 32

typedef __attribute__((ext_vector_type(4))) float f32x4;
typedef __attribute__((ext_vector_type(8))) short bf16x8;

// fp32 -> bf16 bits, round-to-nearest-even
__device__ __forceinline__ unsigned short f2bf(float f) {
  union { float f; unsigned u; } v; v.f = f;
  unsigned r = v.u + 0x7FFF + ((v.u >> 16) & 1);
  return (unsigned short)(r >> 16);
}

// async global->LDS, 16B per lane. LDS dest must be wave-uniform base + lane*16.
__device__ __forceinline__ void gload_lds16(const void* g, void* l) {
  __builtin_amdgcn_global_load_lds(
      (__attribute__((address_space(1))) void*)(g),
      (__attribute__((address_space(3))) void*)(l), 16, 0, 0);
}

// ---------------------------------------------------------------------------
// Kernel 1: router (fp32 exact) + x -> bf16 conversion, one pass over x.
// R2 rewrite: the old token-per-lane global pattern had adjacent lanes 4 KB
// apart -> 64 cache lines per wave instruction -> latency-bound at 26% HBM
// (125 us, WRITE_SIZE 2.2x ideal). New structure:
//   - block owns 64 tokens; loop over 8 chunks of 128 floats.
//   - LOAD phase: coalesced float4 reads (contiguous within rows), bf16
//     convert + coalesced uint2 stores, fp32 staged to LDS tile [64][132].
//     Row stride 132 floats (528 B): b128 granule slot = (row + col4) % 8
//     -> conflict-free ds_write_b128 / ds_read_b128.
//   - COMPUTE phase: lane = token, wave w owns k in [w*16, w*16+16) of the
//     chunk (wave-uniform -> Wg via s_load), ds_read_b128 from the tile.
//   - partial logits reduced through LDS; wave 0 finalizes softmax prob.
// Router math stays fp32-exact (same as reference up to summation order).
// ---------------------------------------------------------------------------
__global__ __launch_bounds__(512) void router_convert(
    const float* __restrict__ x, const float* __restrict__ Wg,
    const float* __restrict__ bg, unsigned short* __restrict__ xb,
    float* __restrict__ p) {
  __shared__ float tile[64][132];        // 33,792 B, padded stride vs b128 slots
  __shared__ float part[8][64][NEXP];    // 16,384 B
  const int t = threadIdx.x;
  const int lane = t & 63;
  const int wu = __builtin_amdgcn_readfirstlane(t >> 6);  // wave id, SGPR
  const int tok0 = blockIdx.x * 64;

  float acc[NEXP];
#pragma unroll
  for (int e = 0; e < NEXP; ++e) acc[e] = 0.f;

  for (int ck = 0; ck < 8; ++ck) {
    // ---- load + convert + LDS stage (coalesced) ----
#pragma unroll
    for (int i = 0; i < 4; ++i) {
      const int idx = i * 512 + t;       // 0..2047 over [64 rows][32 float4]
      const int r = idx >> 5, c4 = idx & 31;
      const size_t goff = (size_t)(tok0 + r) * HDIM + ck * 128 + c4 * 4;
      const float4 v = *(const float4*)(x + goff);
      union { unsigned short us[4]; uint2 u2; } pk;
      pk.us[0] = f2bf(v.x); pk.us[1] = f2bf(v.y);
      pk.us[2] = f2bf(v.z); pk.us[3] = f2bf(v.w);
      *(uint2*)(xb + goff) = pk.u2;
      *(float4*)(&tile[r][c4 * 4]) = v;  // ds_write_b128, conflict-free
    }
    __syncthreads();

    // ---- compute: lane = token, wave-uniform k-range -> scalar Wg loads ----
    const float* wr = Wg + ((size_t)ck * 128 + wu * 16) * NEXP;
#pragma unroll
    for (int q = 0; q < 4; ++q) {
      const float4 f = *(const float4*)(&tile[lane][wu * 16 + q * 4]);
      const float fv[4] = {f.x, f.y, f.z, f.w};
#pragma unroll
      for (int j = 0; j < 4; ++j)
#pragma unroll
        for (int e = 0; e < NEXP; ++e)
          acc[e] += fv[j] * wr[(q * 4 + j) * NEXP + e];
    }
    __syncthreads();
  }

#pragma unroll
  for (int e = 0; e < NEXP; ++e) part[wu][lane][e] = acc[e];
  __syncthreads();

  if (t < 64) {
    float l[NEXP];
#pragma unroll
    for (int e = 0; e < NEXP; ++e) {
      float s = bg[e];
#pragma unroll
      for (int c = 0; c < 8; ++c) s += part[c][t][e];
      l[e] = s;
    }
    float mx = l[0];
#pragma unroll
    for (int e = 1; e < NEXP; ++e) mx = fmaxf(mx, l[e]);
    float s = 0.f;
#pragma unroll
    for (int e = 0; e < NEXP; ++e) s += __expf(l[e] - mx);
    p[tok0 + t] = 1.0f / s;  // softmax prob of the argmax = exp(0)/sum
  }
}

// ---------------------------------------------------------------------------
// Kernel 2: We [k][n] fp32 -> Wt [n][k] bf16 (transpose + convert).
// ---------------------------------------------------------------------------
__global__ __launch_bounds__(256) void transpose_convert(
    const float* __restrict__ We, unsigned short* __restrict__ wt) {
  __shared__ float tile[64][65];
  const int bj = blockIdx.x, bi = blockIdx.y;
  const int tx = threadIdx.x & 63, ty = threadIdx.x >> 6;
#pragma unroll
  for (int i = 0; i < 16; ++i) {
    int row = i * 4 + ty;
    tile[row][tx] = We[(size_t)(bi * 64 + row) * HDIM + bj * 64 + tx];
  }
  __syncthreads();
#pragma unroll
  for (int i = 0; i < 16; ++i) {
    int row = i * 4 + ty;
    wt[(size_t)(bj * 64 + row) * HDIM + bi * 64 + tx] = f2bf(tile[tx][row]);
  }
}

// ---------------------------------------------------------------------------
// Kernel 3: C[m][n] = (A[m][:] @ We[:][n] + be[n]) * p[m], bf16 MFMA.
// m97-ladder structure: 128x128 tile, BK=32, 4 waves (2x2), 4x4 MFMA
// 16x16x32_bf16 per wave, global_load_lds width=16 staging.
// XCD-aware swizzle: HW assigns block i -> XCD i%8. On each XCD, consecutive
// blocks sweep all 8 n-blocks of ONE m-panel before advancing m, and the
// 256 m-panels are partitioned across XCDs -> each A panel is fetched into
// exactly one XCD's L2 once; B (2 MB bf16) is L2-resident per XCD.
// ---------------------------------------------------------------------------
__global__ __launch_bounds__(256) void moe_gemm(
    const unsigned short* __restrict__ A, const unsigned short* __restrict__ Bt,
    const float* __restrict__ be, const float* __restrict__ p,
    float* __restrict__ out) {
  __shared__ __align__(16) unsigned short As[BM * BK];  // [m][k]
  __shared__ __align__(16) unsigned short Bs[BN * BK];  // [n][k]
  const int t = threadIdx.x;

  const unsigned lin = blockIdx.x;            // 2048 blocks
  const unsigned xcd = lin & 7, idx = lin >> 3;
  const int n0 = (int)(idx & 7) * BN;          // n-block inner (8)
  const int m0 = (int)(xcd * 32 + (idx >> 3)) * BM;  // 32 m-panels per XCD

  // staging: 512 chunks of 16B per tile; thread t takes chunks t and t+256.
  const int r0 = t >> 2, c0 = t & 3;
  const unsigned short* ga0 = A + (size_t)(m0 + r0) * HDIM + c0 * 8;
  const unsigned short* ga1 = A + (size_t)(m0 + r0 + 64) * HDIM + c0 * 8;
  const unsigned short* gb0 = Bt + (size_t)(n0 + r0) * HDIM + c0 * 8;
  const unsigned short* gb1 = Bt + (size_t)(n0 + r0 + 64) * HDIM + c0 * 8;
  unsigned short* la0 = As + t * 8;
  unsigned short* la1 = As + (t + 256) * 8;
  unsigned short* lb0 = Bs + t * 8;
  unsigned short* lb1 = Bs + (t + 256) * 8;

  const int lane = t & 63, wid = t >> 6;
  const int wm = (wid >> 1) * 64, wn = (wid & 1) * 64;
  const int col = lane & 15, q = lane >> 4;  // A/B frag: row=col, k=q*8+i

  f32x4 acc[4][4] = {};

  for (int k0 = 0; k0 < HDIM; k0 += BK) {
    gload_lds16(ga0, la0);
    gload_lds16(ga1, la1);
    gload_lds16(gb0, lb0);
    gload_lds16(gb1, lb1);
    ga0 += BK; ga1 += BK; gb0 += BK; gb1 += BK;
    __syncthreads();
    bf16x8 a[4], b[4];
#pragma unroll
    for (int i = 0; i < 4; ++i) {
      a[i] = *(const bf16x8*)(As + (wm + i * 16 + col) * BK + q * 8);
      b[i] = *(const bf16x8*)(Bs + (wn + i * 16 + col) * BK + q * 8);
    }
#pragma unroll
    for (int i = 0; i < 4; ++i)
#pragma unroll
      for (int j = 0; j < 4; ++j)
        acc[i][j] =
            __builtin_amdgcn_mfma_f32_16x16x32_bf16(a[i], b[j], acc[i][j], 0, 0, 0);
    __syncthreads();
  }

  // epilogue: C/D layout col = lane&15 (n), row = q*4 + r (m)  [m89/m91]
  float pv[4][4];
#pragma unroll
  for (int i = 0; i < 4; ++i)
#pragma unroll
    for (int r = 0; r < 4; ++r) pv[i][r] = p[m0 + wm + i * 16 + q * 4 + r];
#pragma unroll
  for (int j = 0; j < 4; ++j) {
    const int n = n0 + wn + j * 16 + col;
    const float bev = be[n];
#pragma unroll
    for (int i = 0; i < 4; ++i) {
#pragma unroll
      for (int r = 0; r < 4; ++r) {
        const int m = m0 + wm + i * 16 + q * 4 + r;
        out[(size_t)m * HDIM + n] = (acc[i][j][r] + bev) * pv[i][r];
      }
    }
  }
}

// ---------------------------------------------------------------------------
extern "C" void kernel_launch(void* const* d_in, const int* in_sizes, int n_in,
                              void* d_out, int out_size, void* d_ws, size_t ws_size,
                              hipStream_t stream) {
  const float* x  = (const float*)d_in[0];
  const float* Wg = (const float*)d_in[1];
  const float* bg = (const float*)d_in[2];
  const float* We = (const float*)d_in[3];
  const float* be = (const float*)d_in[4];
  float* out = (float*)d_out;

  // workspace layout (needs 69,337,088 B):
  char* ws = (char*)d_ws;
  unsigned short* xb = (unsigned short*)ws;                         // 67,108,864 B
  unsigned short* wt = (unsigned short*)(ws + (size_t)67108864);    //  2,097,152 B
  float* p = (float*)(ws + (size_t)67108864 + 2097152);             //    131,072 B

  router_convert<<<NTOK / 64, 512, 0, stream>>>(x, Wg, bg, xb, p);
  transpose_convert<<<dim3(16, 16), 256, 0, stream>>>(We, wt);
  moe_gemm<<<2048, 256, 0, stream>>>(xb, wt, be, p, out);
}